// Round 10
// baseline (358.302 us; speedup 1.0000x reference)
//
#include <hip/hip_runtime.h>
#include <math.h>

#define HID 128
#define HEADS 4
#define NEG_SLOPE 0.2f
#define R1B 512    // reduce1 grid
#define BCAP 8192  // per-bucket arena capacity (mean 4096, +64 sigma)
#define ACHUNK 4096

typedef float f32x4 __attribute__((ext_vector_type(4)));
typedef _Float16 f16x8 __attribute__((ext_vector_type(8)));
typedef _Float16 f16x4 __attribute__((ext_vector_type(4)));
typedef _Float16 f16x2 __attribute__((ext_vector_type(2)));

#if defined(__has_builtin)
#if __has_builtin(__builtin_amdgcn_fdot2)
#define HAVE_FDOT2 1
#endif
#endif

// ---------------- helpers ----------------

__device__ inline f16x2 absh2(f16x2 v) {
    unsigned u = __builtin_bit_cast(unsigned, v) & 0x7FFF7FFFu;
    return __builtin_bit_cast(f16x2, u);
}

__device__ inline f16x8 zero8() {
    f16x8 z;
    #pragma unroll
    for (int i = 0; i < 8; i++) z[i] = (_Float16)0.f;
    return z;
}

// quad_perm butterfly add via DPP (head groups are hardware quads).
template <int CTRL>
__device__ inline float qp_xor_add(float x) {
    int y = __builtin_amdgcn_update_dpp(0, __builtin_bit_cast(int, x),
                                        CTRL, 0xF, 0xF, true);
    return x + __builtin_bit_cast(float, y);
}

// per-edge logit: leaky_relu(xl+xr) . att  (packed fp16, fdot2 accumulate)
__device__ inline float edge_logit8(f16x8 c,
                                    f16x2 xr0, f16x2 xr1, f16x2 xr2, f16x2 xr3,
                                    f16x2 a0, f16x2 a1, f16x2 a2, f16x2 a3) {
    const f16x2 k06 = (f16x2){(_Float16)0.6f, (_Float16)0.6f};
    const f16x2 k04 = (f16x2){(_Float16)0.4f, (_Float16)0.4f};
    f16x2 c0 = __builtin_shufflevector(c, c, 0, 1);
    f16x2 c1 = __builtin_shufflevector(c, c, 2, 3);
    f16x2 c2 = __builtin_shufflevector(c, c, 4, 5);
    f16x2 c3 = __builtin_shufflevector(c, c, 6, 7);
    f16x2 u0 = c0 + xr0, u1 = c1 + xr1, u2 = c2 + xr2, u3 = c3 + xr3;
    f16x2 l0 = u0 * k06 + absh2(u0) * k04;   // leaky_relu, packed
    f16x2 l1 = u1 * k06 + absh2(u1) * k04;
    f16x2 l2 = u2 * k06 + absh2(u2) * k04;
    f16x2 l3 = u3 * k06 + absh2(u3) * k04;
#ifdef HAVE_FDOT2
    float p = __builtin_amdgcn_fdot2(l0, a0, 0.f, false);
    p = __builtin_amdgcn_fdot2(l1, a1, p, false);
    p = __builtin_amdgcn_fdot2(l2, a2, p, false);
    p = __builtin_amdgcn_fdot2(l3, a3, p, false);
#else
    float p = (float)l0[0] * (float)a0[0] + (float)l0[1] * (float)a0[1]
            + (float)l1[0] * (float)a1[0] + (float)l1[1] * (float)a1[1]
            + (float)l2[0] * (float)a2[0] + (float)l2[1] * (float)a2[1]
            + (float)l3[0] * (float)a3[0] + (float)l3[1] * (float)a3[1];
#endif
    return p;
}

// accumulate one weighted row into acc16[0..3] with LITERAL shuffle indices
#define ACC_ROW(WP, R)                                                        \
    acc16[0] += (WP) * __builtin_shufflevector((R), (R), 0, 1);               \
    acc16[1] += (WP) * __builtin_shufflevector((R), (R), 2, 3);               \
    acc16[2] += (WP) * __builtin_shufflevector((R), (R), 4, 5);               \
    acc16[3] += (WP) * __builtin_shufflevector((R), (R), 6, 7);

// ---------------- Fused prep: embed + W convert + binA (CSR phase A) ----------------
// gcnt is pre-zeroed by hipMemsetAsync, so binA blocks are independent of
// embed/convert blocks and fill idle CU slots alongside them (binA is
// latency-bound at 196 blocks; embed is bandwidth-bound). Record =
// (src<<8)|(dst&255) binned into per-bucket arenas.

__global__ __launch_bounds__(256) void k_prep(const float* __restrict__ nf, const float* __restrict__ We,
                                              const float* __restrict__ be, _Float16* __restrict__ xh,
                                              int N,
                                              const float* __restrict__ Wl, const float* __restrict__ Wr,
                                              _Float16* __restrict__ WfL, _Float16* __restrict__ WfR,
                                              int nW,
                                              const int* __restrict__ src, const int* __restrict__ dst,
                                              int E, int* __restrict__ gcnt, int* __restrict__ arena) {
    __shared__ int lh[256];
    __shared__ int lbase[256];
    __shared__ unsigned short lrank[ACHUNK];
    __shared__ float f[2][11];
    const int nEmb = (N + 1) / 2;
    const int bid = blockIdx.x;
    const int tid = threadIdx.x;

    if (bid < nEmb) {
        // ---- embed: 2 nodes per block ----
        const int sub = tid >> 7;
        const int h   = tid & 127;
        const int n   = bid * 2 + sub;
        if (n < N && h < 11) f[sub][h] = nf[(size_t)n * 11 + h];
        __syncthreads();
        if (n >= N) return;
        float acc = be[h];
        #pragma unroll
        for (int k = 0; k < 11; k++) acc += f[sub][k] * We[h * 11 + k];
        xh[(size_t)n * HID + h] = (_Float16)fmaxf(acc, 0.f);
    } else if (bid < nEmb + 128) {
        // ---- W fp16 conversion: 64 blocks per matrix ----
        const int tb = bid - nEmb;
        const int mat = tb >> 6;
        const float* x = mat ? Wr : Wl;
        _Float16*    o = mat ? WfR : WfL;
        int base = ((tb & 63) * 256 + tid) * 4;
        if (base >= nW) return;
        float4 v = *(const float4*)(x + base);
        f16x4 h = {(_Float16)v.x, (_Float16)v.y, (_Float16)v.z, (_Float16)v.w};
        *(f16x4*)(o + base) = h;
    } else {
        // ---- binA: bin ACHUNK edges into bucket arenas ----
        lh[tid] = 0;
        __syncthreads();
        const int e0 = (bid - nEmb - 128) * ACHUNK;
        #pragma unroll
        for (int i = 0; i < ACHUNK / 256; i++) {
            int e = e0 + i * 256 + tid;
            if (e < E) {
                int b = dst[e] >> 8;
                lrank[i * 256 + tid] = (unsigned short)atomicAdd(&lh[b], 1);
            }
        }
        __syncthreads();
        if (lh[tid] > 0) lbase[tid] = atomicAdd(&gcnt[tid], lh[tid]);
        __syncthreads();
        #pragma unroll
        for (int i = 0; i < ACHUNK / 256; i++) {
            int e = e0 + i * 256 + tid;
            if (e < E) {
                int d = dst[e];
                int b = d >> 8;
                arena[b * BCAP + lbase[b] + lrank[i * 256 + tid]] = (src[e] << 8) | (d & 255);
            }
        }
    }
}

// ---------------- CSR phase B: per bucket, rowptr + csr_off ----------------
// Direct scattered csr_off writes (dense within the ~16KB bucket segment ->
// L2 merges into full lines; staging pass removed: at 196 blocks / 256 CUs
// the kernel is grid-limited, so the LDS round-trip + extra barriers were
// pure latency).

__global__ __launch_bounds__(256) void k_binB(const int* __restrict__ arena, const int* __restrict__ gcnt,
                                              int N, int E,
                                              int* __restrict__ rowptr, int* __restrict__ csr_off) {
    __shared__ int ncnt[256];
    __shared__ int sbuf[256];
    __shared__ int nstart[256];
    __shared__ int exv[256];
    __shared__ unsigned short rk[BCAP];
    const int b = blockIdx.x, tid = threadIdx.x;

    // bucket-prefix scan (gcnt[tid]=0 for tid>=nbk via memset)
    int gv = gcnt[tid];
    sbuf[tid] = gv;
    __syncthreads();
    for (int off = 1; off < 256; off <<= 1) {
        int t = (tid >= off) ? sbuf[tid - off] : 0;
        __syncthreads();
        sbuf[tid] += t;
        __syncthreads();
    }
    exv[tid] = sbuf[tid] - gv;    // exclusive prefix
    if (b == 0 && tid == 0) rowptr[N] = E;
    __syncthreads();
    const int seg = exv[b];
    const int cnt = gcnt[b];

    ncnt[tid] = 0;
    __syncthreads();
    for (int k = tid; k < cnt; k += 256) {
        int v = arena[b * BCAP + k];
        rk[k] = (unsigned short)atomicAdd(&ncnt[v & 255], 1);
    }
    __syncthreads();
    int c = ncnt[tid];
    sbuf[tid] = c;
    __syncthreads();
    for (int off = 1; off < 256; off <<= 1) {
        int t = (tid >= off) ? sbuf[tid - off] : 0;
        __syncthreads();
        sbuf[tid] += t;
        __syncthreads();
    }
    int myStart = sbuf[tid] - c;   // exclusive
    nstart[tid] = myStart;
    int n = b * 256 + tid;
    if (n < N) rowptr[n] = seg + myStart;
    __syncthreads();
    for (int k = tid; k < cnt; k += 256) {
        int v = arena[b * BCAP + k];
        int pos = nstart[v & 255] + rk[k];
        csr_off[seg + pos] = v & 0xFFFFFF00;
    }
}

// ---------------- MFMA linear, LDS-resident fp16 W, 2 A-tiles/wave ----------------
// 256 threads / 128 nodes per block (3.1 blocks/CU); epilogue through LDS
// (node stride 136 halves) -> coalesced 16B stores.

__global__ __launch_bounds__(256, 4) void k_linear_mfma(
        const _Float16* __restrict__ xh,
        const _Float16* __restrict__ WfL, const _Float16* __restrict__ WfR,
        const float* __restrict__ bl, const float* __restrict__ br,
        _Float16* __restrict__ xlh, _Float16* __restrict__ xrh, int N) {
    __shared__ _Float16 lds[16384];   // W fp16 swizzled; reused for C transpose
    const int t   = threadIdx.x;
    const int mat = blockIdx.y;
    const _Float16* W = mat ? WfR : WfL;

    for (int g = t; g < 2048; g += 256) {
        int r = g >> 4, cc = g & 15;
        int dsto = r * 128 + ((cc ^ (r & 7)) << 3);      // half units
        *(float4*)&lds[dsto] = *(const float4*)(W + g * 8);
    }
    __syncthreads();

    const int wave = t >> 6;
    const int lane = t & 63;
    const int l16  = lane & 15;
    const int quad = lane >> 4;
    const int n0   = blockIdx.x * 128 + wave * 32;

    int arow0 = n0 + l16;
    int arow1 = n0 + 16 + l16;
    if (arow0 >= N) arow0 = N - 1;     // clamp loads; stores guarded below
    if (arow1 >= N) arow1 = N - 1;

    f32x4 acc[2][8];
    #pragma unroll
    for (int u = 0; u < 2; u++)
        #pragma unroll
        for (int s = 0; s < 8; s++) acc[u][s] = (f32x4){0.f, 0.f, 0.f, 0.f};

    #pragma unroll
    for (int k0 = 0; k0 < HID; k0 += 32) {
        f16x8 a0 = *(const f16x8*)(xh + arow0 * HID + k0 + quad * 8);
        f16x8 a1 = *(const f16x8*)(xh + arow1 * HID + k0 + quad * 8);
        const int cc = (k0 >> 3) + quad;
        #pragma unroll
        for (int s = 0; s < 8; s++) {
            const int row = s * 16 + l16;
            const int off = row * 128 + ((cc ^ (l16 & 7)) << 3);
            f16x8 b = *(const f16x8*)&lds[off];
            acc[0][s] = __builtin_amdgcn_mfma_f32_16x16x32_f16(a0, b, acc[0][s], 0, 0, 0);
            acc[1][s] = __builtin_amdgcn_mfma_f32_16x16x32_f16(a1, b, acc[1][s], 0, 0, 0);
        }
    }

    const float* bias = mat ? br : bl;
    _Float16* dst = mat ? xrh : xlh;
    const int wl = wave & 1;            // wave index within a round

    #pragma unroll
    for (int round = 0; round < 2; round++) {
        __syncthreads();                 // W (or previous round) fully consumed
        if ((wave >> 1) == round) {
            #pragma unroll
            for (int s = 0; s < 8; s++) {
                int col = s * 16 + l16;
                float bv = bias[col];
                #pragma unroll
                for (int u = 0; u < 2; u++) {
                    #pragma unroll
                    for (int r = 0; r < 4; r++) {
                        int nd = wl * 32 + u * 16 + quad * 4 + r;   // 0..63
                        lds[nd * 136 + col] = (_Float16)(acc[u][s][r] + bv);
                    }
                }
            }
        }
        __syncthreads();
        // coalesced dump: 64 nodes x 256B = 1024 x 16B units
        const int base_node = blockIdx.x * 128 + round * 64;
        #pragma unroll
        for (int it = 0; it < 4; it++) {
            int idx = it * 256 + t;
            int node = base_node + (idx >> 4);
            if (node < N)
                *(float4*)(dst + (size_t)node * HID + (idx & 15) * 8) =
                    *(float4*)&lds[(idx >> 4) * 136 + (idx & 15) * 8];
        }
    }
}

// ---------------- Fused attention: wave per node, 4 edge streams ----------------
// 6-pair upfront loads (gather MLP); per-pair exec-guarded compute. Slow path
// (deg>=25, ~2%): depth-2 predicated pipeline.

__global__ __launch_bounds__(256, 8) void k_attn(const _Float16* __restrict__ xlh, const _Float16* __restrict__ xrh,
                                              const int* __restrict__ rowptr, const int* __restrict__ csr_off,
                                              const float* __restrict__ att, const float* __restrict__ bias,
                                              const _Float16* __restrict__ xres, _Float16* __restrict__ outx,
                                              float* __restrict__ out,
                                              int add_res, int want_half, int N) {
    const int wave = threadIdx.x >> 6;
    const int lane = threadIdx.x & 63;
    const int strm = lane >> 4;          // edge stream 0..3
    const int l16  = lane & 15;          // channels [8*l16, 8*l16+8); head = l16>>2
    const int n = blockIdx.x * 4 + wave;
    if (n >= N) return;

    const float4 aA = *(const float4*)(att + 8 * l16);
    const float4 aB = *(const float4*)(att + 8 * l16 + 4);
    const f16x2 a0 = (f16x2){(_Float16)aA.x, (_Float16)aA.y};
    const f16x2 a1 = (f16x2){(_Float16)aA.z, (_Float16)aA.w};
    const f16x2 a2 = (f16x2){(_Float16)aB.x, (_Float16)aB.y};
    const f16x2 a3 = (f16x2){(_Float16)aB.z, (_Float16)aB.w};
    const f16x8 xrv = *(const f16x8*)(xrh + (size_t)n * HID + 8 * l16);
    const f16x2 xr0 = __builtin_shufflevector(xrv, xrv, 0, 1);
    const f16x2 xr1 = __builtin_shufflevector(xrv, xrv, 2, 3);
    const f16x2 xr2 = __builtin_shufflevector(xrv, xrv, 4, 5);
    const f16x2 xr3 = __builtin_shufflevector(xrv, xrv, 6, 7);
    const int s0 = rowptr[n], s1 = rowptr[n + 1];
    const int deg = s1 - s0;

    float den = 0.f;
    f16x2 acc16[4];
    #pragma unroll
    for (int q = 0; q < 4; q++) acc16[q] = (f16x2){(_Float16)0.f, (_Float16)0.f};

    const char* xlb = (const char*)xlh + l16 * 16;  // lane's 16B slice within a row
    const int j = s0 + 2 * strm;                    // stream's first edge

    if (deg > 0 && deg <= 24) {
        // ---- fast path: loads upfront, compute per-pair exec-guarded ----
        const int last = s1 - 1;
        f16x8 r0 = zero8(), r1 = zero8(), r2 = zero8(),
              r3 = zero8(), r4 = zero8(), r5 = zero8();
        if (j < s1) {
            int o0 = csr_off[j];
            int o1 = csr_off[min(j + 1, last)];
            r0 = *(const f16x8*)(xlb + o0);
            r1 = *(const f16x8*)(xlb + o1);
        }
        if (j + 8 < s1) {
            int o2 = csr_off[j + 8];
            int o3 = csr_off[min(j + 9, last)];
            r2 = *(const f16x8*)(xlb + o2);
            r3 = *(const f16x8*)(xlb + o3);
        }
        if (j + 16 < s1) {
            int o4 = csr_off[j + 16];
            int o5 = csr_off[min(j + 17, last)];
            r4 = *(const f16x8*)(xlb + o4);
            r5 = *(const f16x8*)(xlb + o5);
        }

        if (j < s1) {       // pair 0 (execz-skips only for tiny tails)
            float p0 = edge_logit8(r0, xr0, xr1, xr2, xr3, a0, a1, a2, a3);
            float p1 = edge_logit8(r1, xr0, xr1, xr2, xr3, a0, a1, a2, a3);
            p0 = qp_xor_add<0xB1>(p0); p0 = qp_xor_add<0x4E>(p0);
            p1 = qp_xor_add<0xB1>(p1); p1 = qp_xor_add<0x4E>(p1);
            float w0 = __expf(p0);
            float w1 = (j + 1 < s1) ? __expf(p1) : 0.f;
            den += w0 + w1;
            f16x2 wp0 = (f16x2){(_Float16)w0, (_Float16)w0};
            f16x2 wp1 = (f16x2){(_Float16)w1, (_Float16)w1};
            ACC_ROW(wp0, r0)
            ACC_ROW(wp1, r1)
        }
        if (j + 8 < s1) {   // pair 1 (execz-skips whole wave when deg<=8)
            float p2 = edge_logit8(r2, xr0, xr1, xr2, xr3, a0, a1, a2, a3);
            float p3 = edge_logit8(r3, xr0, xr1, xr2, xr3, a0, a1, a2, a3);
            p2 = qp_xor_add<0xB1>(p2); p2 = qp_xor_add<0x4E>(p2);
            p3 = qp_xor_add<0xB1>(p3); p3 = qp_xor_add<0x4E>(p3);
            float w2 = __expf(p2);
            float w3 = (j + 9 < s1) ? __expf(p3) : 0.f;
            den += w2 + w3;
            f16x2 wp2 = (f16x2){(_Float16)w2, (_Float16)w2};
            f16x2 wp3 = (f16x2){(_Float16)w3, (_Float16)w3};
            ACC_ROW(wp2, r2)
            ACC_ROW(wp3, r3)
        }
        if (j + 16 < s1) {  // pair 2 (execz-skips whole wave when deg<=16)
            float p4 = edge_logit8(r4, xr0, xr1, xr2, xr3, a0, a1, a2, a3);
            float p5 = edge_logit8(r5, xr0, xr1, xr2, xr3, a0, a1, a2, a3);
            p4 = qp_xor_add<0xB1>(p4); p4 = qp_xor_add<0x4E>(p4);
            p5 = qp_xor_add<0xB1>(p5); p5 = qp_xor_add<0x4E>(p5);
            float w4 = __expf(p4);
            float w5 = (j + 17 < s1) ? __expf(p5) : 0.f;
            den += w4 + w5;
            f16x2 wp4 = (f16x2){(_Float16)w4, (_Float16)w4};
            f16x2 wp5 = (f16x2){(_Float16)w5, (_Float16)w5};
            ACC_ROW(wp4, r4)
            ACC_ROW(wp5, r5)
        }
    } else if (deg > 24) {
        // ---- slow path: depth-2 pipeline, predicated prefetch ----
        const int last = s1 - 1;
        int jj = j;
        // prologue: all 4 rows valid (deg>=25 => jj+9 <= s0+15 < s1)
        f16x8 pa0 = *(const f16x8*)(xlb + csr_off[jj]);
        f16x8 pb0 = *(const f16x8*)(xlb + csr_off[jj + 1]);
        f16x8 pa1 = *(const f16x8*)(xlb + csr_off[jj + 8]);
        f16x8 pb1 = *(const f16x8*)(xlb + csr_off[jj + 9]);
        int oa = csr_off[min(jj + 16, last)];
        int ob = csr_off[min(jj + 17, last)];
        while (jj < s1) {
            f16x8 ca = pa0, cb = pb0;
            pa0 = pa1; pb0 = pb1;
            if (jj + 16 < s1) {          // predicated prefetch: no dup gathers
                pa1 = *(const f16x8*)(xlb + oa);
                pb1 = *(const f16x8*)(xlb + ob);
                oa = csr_off[min(jj + 24, last)];
                ob = csr_off[min(jj + 25, last)];
            } else { pa1 = zero8(); pb1 = zero8(); }

            float pa = edge_logit8(ca, xr0, xr1, xr2, xr3, a0, a1, a2, a3);
            float pb = edge_logit8(cb, xr0, xr1, xr2, xr3, a0, a1, a2, a3);
            pa = qp_xor_add<0xB1>(pa); pa = qp_xor_add<0x4E>(pa);
            pb = qp_xor_add<0xB1>(pb); pb = qp_xor_add<0x4E>(pb);
            float wa = __expf(pa);
            float wb = (jj + 1 < s1) ? __expf(pb) : 0.f;
            den += wa + wb;
            f16x2 wpa = (f16x2){(_Float16)wa, (_Float16)wa};
            f16x2 wpb = (f16x2){(_Float16)wb, (_Float16)wb};
            ACC_ROW(wpa, ca)
            ACC_ROW(wpb, cb)
            jj += 8;
        }
    }

    // merge the four streams (lane stride 16/32) on packed f16x2
    den += __shfl_xor(den, 16);
    den += __shfl_xor(den, 32);
    #pragma unroll
    for (int q = 0; q < 4; q++) {
        float pk = __builtin_bit_cast(float, acc16[q]);
        acc16[q] += __builtin_bit_cast(f16x2, __shfl_xor(pk, 16));
        pk = __builtin_bit_cast(float, acc16[q]);
        acc16[q] += __builtin_bit_cast(f16x2, __shfl_xor(pk, 32));
    }

    if (strm == 0) {
        float acc[8];
        #pragma unroll
        for (int q = 0; q < 4; q++) {
            acc[2 * q]     = (float)acc16[q][0];
            acc[2 * q + 1] = (float)acc16[q][1];
        }
        float4 bA = *(const float4*)(bias + 8 * l16);
        float4 bB = *(const float4*)(bias + 8 * l16 + 4);
        float b[8] = {bA.x, bA.y, bA.z, bA.w, bB.x, bB.y, bB.z, bB.w};
        float inv = (den > 0.f) ? 1.f / den : 0.f;
        float v[8];
        #pragma unroll
        for (int q = 0; q < 8; q++) v[q] = fmaxf(acc[q] * inv + b[q], 0.f);
        if (add_res) {
            f16x8 r = *(const f16x8*)(xres + (size_t)n * HID + 8 * l16);
            #pragma unroll
            for (int q = 0; q < 8; q++) v[q] += (float)r[q];
        }
        if (want_half) {
            f16x8 h;
            #pragma unroll
            for (int q = 0; q < 8; q++) h[q] = (_Float16)v[q];
            *(f16x8*)(outx + (size_t)n * HID + 8 * l16) = h;
        } else {
            *(float4*)(out + (size_t)n * HID + 8 * l16)     = make_float4(v[0], v[1], v[2], v[3]);
            *(float4*)(out + (size_t)n * HID + 8 * l16 + 4) = make_float4(v[4], v[5], v[6], v[7]);
        }
    }
}

// ---------------- Graph readout: mean + max over nodes ----------------

__global__ __launch_bounds__(256) void k_reduce1(const float* __restrict__ x, int N,
                                                 float* __restrict__ psum, float* __restrict__ pmax) {
    __shared__ float ls[8][HID];
    __shared__ float lm[8][HID];
    const int c4 = (threadIdx.x & 31) << 2;   // channel base
    const int rl = threadIdx.x >> 5;          // row lane 0..7
    const int per = (N + gridDim.x - 1) / gridDim.x;
    const int n0 = blockIdx.x * per, n1 = min(N, n0 + per);
    float4 s = make_float4(0.f, 0.f, 0.f, 0.f);
    float4 m = make_float4(-INFINITY, -INFINITY, -INFINITY, -INFINITY);
    for (int n = n0 + rl; n < n1; n += 8) {
        float4 v = *(const float4*)(x + (size_t)n * HID + c4);
        s.x += v.x; s.y += v.y; s.z += v.z; s.w += v.w;
        m.x = fmaxf(m.x, v.x); m.y = fmaxf(m.y, v.y);
        m.z = fmaxf(m.z, v.z); m.w = fmaxf(m.w, v.w);
    }
    *(float4*)&ls[rl][c4] = s;
    *(float4*)&lm[rl][c4] = m;
    __syncthreads();
    if (rl < 4) {
        float4 a = *(float4*)&ls[rl][c4], bq = *(float4*)&ls[rl + 4][c4];
        a.x += bq.x; a.y += bq.y; a.z += bq.z; a.w += bq.w;
        *(float4*)&ls[rl][c4] = a;
        float4 am = *(float4*)&lm[rl][c4], bm = *(float4*)&lm[rl + 4][c4];
        am.x = fmaxf(am.x, bm.x); am.y = fmaxf(am.y, bm.y);
        am.z = fmaxf(am.z, bm.z); am.w = fmaxf(am.w, bm.w);
        *(float4*)&lm[rl][c4] = am;
    }
    __syncthreads();
    if (rl < 2) {
        float4 a = *(float4*)&ls[rl][c4], bq = *(float4*)&ls[rl + 2][c4];
        a.x += bq.x; a.y += bq.y; a.z += bq.z; a.w += bq.w;
        *(float4*)&ls[rl][c4] = a;
        float4 am = *(float4*)&lm[rl][c4], bm = *(float4*)&lm[rl + 2][c4];
        am.x = fmaxf(am.x, bm.x); am.y = fmaxf(am.y, bm.y);
        am.z = fmaxf(am.z, bm.z); am.w = fmaxf(am.w, bm.w);
        *(float4*)&lm[rl][c4] = am;
    }
    __syncthreads();
    if (rl == 0) {
        float4 a = *(float4*)&ls[0][c4], bq = *(float4*)&ls[1][c4];
        a.x += bq.x; a.y += bq.y; a.z += bq.z; a.w += bq.w;
        *(float4*)(psum + (size_t)blockIdx.x * HID + c4) = a;
        float4 am = *(float4*)&lm[0][c4], bm = *(float4*)&lm[1][c4];
        am.x = fmaxf(am.x, bm.x); am.y = fmaxf(am.y, bm.y);
        am.z = fmaxf(am.z, bm.z); am.w = fmaxf(am.w, bm.w);
        *(float4*)(pmax + (size_t)blockIdx.x * HID + c4) = am;
    }
}

__global__ __launch_bounds__(1024) void k_reduce2(const float* __restrict__ psum, const float* __restrict__ pmax,
                                                  int nb, float* __restrict__ out, float invN) {
    __shared__ float ss[8][HID];
    __shared__ float sm[8][HID];
    int h = threadIdx.x & 127;
    int c = threadIdx.x >> 7;          // chunk 0..7
    int per = nb >> 3;
    float s = 0.f, m = -INFINITY;
    for (int b = c * per; b < (c + 1) * per; b++) {
        s += psum[b * HID + h];
        m = fmaxf(m, pmax[b * HID + h]);
    }
    ss[c][h] = s; sm[c][h] = m;
    __syncthreads();
    if (c < 4) { ss[c][h] += ss[c + 4][h]; sm[c][h] = fmaxf(sm[c][h], sm[c + 4][h]); }
    __syncthreads();
    if (c < 2) { ss[c][h] += ss[c + 2][h]; sm[c][h] = fmaxf(sm[c][h], sm[c + 2][h]); }
    __syncthreads();
    if (c == 0) {
        out[h] = (ss[0][h] + ss[1][h]) * invN;
        out[HID + h] = fmaxf(sm[0][h], sm[1][h]);
    }
}

// ---------------- Launch ----------------

extern "C" void kernel_launch(void* const* d_in, const int* in_sizes, int n_in,
                              void* d_out, int out_size, void* d_ws, size_t ws_size,
                              hipStream_t stream) {
    const float* nf    = (const float*)d_in[0];
    const int*   ei    = (const int*)d_in[1];
    const float* W_emb = (const float*)d_in[3];
    const float* b_emb = (const float*)d_in[4];
    const float* Wl    = (const float*)d_in[5];
    const float* bl    = (const float*)d_in[6];
    const float* Wr    = (const float*)d_in[7];
    const float* br    = (const float*)d_in[8];
    const float* att   = (const float*)d_in[9];
    const float* bias  = (const float*)d_in[10];

    const int N = in_sizes[0] / 11;
    const int E = in_sizes[1] / 2;
    const int* src = ei;
    const int* dst = ei + E;

    float* out  = (float*)d_out;
    float* xout = out + 2 * HID;

    // workspace carve-up
    char* w = (char*)d_ws;
    _Float16* xlh  = (_Float16*)w; w += (size_t)N * HID * 2;
    _Float16* xrh  = (_Float16*)w; w += (size_t)N * HID * 2;
    _Float16* xA   = (_Float16*)w; w += (size_t)N * HID * 2;
    _Float16* xB   = (_Float16*)w; w += (size_t)N * HID * 2;
    _Float16* WfL  = (_Float16*)w; w += (size_t)4 * HID * HID * 2;
    _Float16* WfR  = (_Float16*)w; w += (size_t)4 * HID * HID * 2;
    int*   gcnt    = (int*)w;   w += (size_t)256 * 4;
    int*   rowptr  = (int*)w;   w += (size_t)(N + 1) * 4;
    int*   arena   = (int*)w;   w += (size_t)256 * BCAP * 4;
    int*   csr_off = (int*)w;   w += (size_t)E * 4;
    float* psum    = (float*)w; w += (size_t)R1B * HID * 4;
    float* pmax    = (float*)w; w += (size_t)R1B * HID * 4;

    const int nbk = (N + 255) >> 8;       // 196 buckets
    const int nbkA = (E + ACHUNK - 1) / ACHUNK;
    const int nW = 4 * HID * HID;

    // zero gcnt up-front so binA (fused into k_prep) has no ordering dependence
    hipMemsetAsync(gcnt, 0, 256 * sizeof(int), stream);

    // fused: embedding + weight fp16 conversion + CSR phase A
    const int nEmb = (N + 1) / 2;
    k_prep<<<nEmb + 128 + nbkA, 256, 0, stream>>>(nf, W_emb, b_emb, xA, N,
                                                  Wl, Wr, WfL, WfR, nW,
                                                  src, dst, E, gcnt, arena);

    // CSR phase B (self-scans bucket prefix; direct scattered csr_off writes)
    k_binB<<<nbk, 256, 0, stream>>>(arena, gcnt, N, E, rowptr, csr_off);

    dim3 lgrid((N + 127) / 128, 2);
    for (int i = 0; i < 4; i++) {
        // ping-pong: even layers read A write B, odd layers read B write A
        const _Float16* xin = (i & 1) ? xB : xA;
        _Float16* xo        = (i & 1) ? xA : xB;
        k_linear_mfma<<<lgrid, 256, 0, stream>>>(xin,
                                                 WfL + (size_t)i * HID * HID, WfR + (size_t)i * HID * HID,
                                                 bl + i * HID, br + i * HID, xlh, xrh, N);
        k_attn<<<(N + 3) / 4, 256, 0, stream>>>(xlh, xrh, rowptr, csr_off,
                                                att + i * HEADS * 32, bias + i * HID,
                                                xin, xo, xout,
                                                i > 0 ? 1 : 0, i < 3 ? 1 : 0, N);
    }

    k_reduce1<<<R1B, 256, 0, stream>>>(xout, N, psum, pmax);
    k_reduce2<<<1, 1024, 0, stream>>>(psum, pmax, R1B, out, 1.0f / N);
}

// Round 11
// 344.303 us; speedup vs baseline: 1.0407x; 1.0407x over previous
//
#include <hip/hip_runtime.h>
#include <math.h>

#define HID 128
#define HEADS 4
#define NEG_SLOPE 0.2f
#define R1B 512    // reduce1 grid
#define BCAP 8192  // per-bucket arena capacity (mean 4096, +64 sigma)
#define ACHUNK 4096
#define EMBB 2048  // embed grid-stride blocks

typedef float f32x4 __attribute__((ext_vector_type(4)));
typedef _Float16 f16x8 __attribute__((ext_vector_type(8)));
typedef _Float16 f16x4 __attribute__((ext_vector_type(4)));
typedef _Float16 f16x2 __attribute__((ext_vector_type(2)));

#if defined(__has_builtin)
#if __has_builtin(__builtin_amdgcn_fdot2)
#define HAVE_FDOT2 1
#endif
#endif

// ---------------- helpers ----------------

__device__ inline f16x2 absh2(f16x2 v) {
    unsigned u = __builtin_bit_cast(unsigned, v) & 0x7FFF7FFFu;
    return __builtin_bit_cast(f16x2, u);
}

__device__ inline f16x8 zero8() {
    f16x8 z;
    #pragma unroll
    for (int i = 0; i < 8; i++) z[i] = (_Float16)0.f;
    return z;
}

// quad_perm butterfly add via DPP (head groups are hardware quads).
template <int CTRL>
__device__ inline float qp_xor_add(float x) {
    int y = __builtin_amdgcn_update_dpp(0, __builtin_bit_cast(int, x),
                                        CTRL, 0xF, 0xF, true);
    return x + __builtin_bit_cast(float, y);
}

// per-edge logit: leaky_relu(xl+xr) . att  (packed fp16, fdot2 accumulate)
__device__ inline float edge_logit8(f16x8 c,
                                    f16x2 xr0, f16x2 xr1, f16x2 xr2, f16x2 xr3,
                                    f16x2 a0, f16x2 a1, f16x2 a2, f16x2 a3) {
    const f16x2 k06 = (f16x2){(_Float16)0.6f, (_Float16)0.6f};
    const f16x2 k04 = (f16x2){(_Float16)0.4f, (_Float16)0.4f};
    f16x2 c0 = __builtin_shufflevector(c, c, 0, 1);
    f16x2 c1 = __builtin_shufflevector(c, c, 2, 3);
    f16x2 c2 = __builtin_shufflevector(c, c, 4, 5);
    f16x2 c3 = __builtin_shufflevector(c, c, 6, 7);
    f16x2 u0 = c0 + xr0, u1 = c1 + xr1, u2 = c2 + xr2, u3 = c3 + xr3;
    f16x2 l0 = u0 * k06 + absh2(u0) * k04;   // leaky_relu, packed
    f16x2 l1 = u1 * k06 + absh2(u1) * k04;
    f16x2 l2 = u2 * k06 + absh2(u2) * k04;
    f16x2 l3 = u3 * k06 + absh2(u3) * k04;
#ifdef HAVE_FDOT2
    float p = __builtin_amdgcn_fdot2(l0, a0, 0.f, false);
    p = __builtin_amdgcn_fdot2(l1, a1, p, false);
    p = __builtin_amdgcn_fdot2(l2, a2, p, false);
    p = __builtin_amdgcn_fdot2(l3, a3, p, false);
#else
    float p = (float)l0[0] * (float)a0[0] + (float)l0[1] * (float)a0[1]
            + (float)l1[0] * (float)a1[0] + (float)l1[1] * (float)a1[1]
            + (float)l2[0] * (float)a2[0] + (float)l2[1] * (float)a2[1]
            + (float)l3[0] * (float)a3[0] + (float)l3[1] * (float)a3[1];
#endif
    return p;
}

// accumulate one weighted row into acc16[0..3] with LITERAL shuffle indices
#define ACC_ROW(WP, R)                                                        \
    acc16[0] += (WP) * __builtin_shufflevector((R), (R), 0, 1);               \
    acc16[1] += (WP) * __builtin_shufflevector((R), (R), 2, 3);               \
    acc16[2] += (WP) * __builtin_shufflevector((R), (R), 4, 5);               \
    acc16[3] += (WP) * __builtin_shufflevector((R), (R), 6, 7);

// ---------------- Prep: grid-stride embed + W fp16 convert ----------------
// Embed restructured (R10 post-mortem: old 2-nodes-per-block embed was
// 50 us at 5% HBM -- pure per-block fixed cost). Now: 2048 blocks, thread
// owns channel h, W-row+bias hoisted to registers, node loop grid-strided,
// no barriers. Feature-row reads are 44B broadcasts (L1-hit); stores are
// 256B contiguous per 128-group. Convert blocks: 64/matrix; first zeroes
// gcnt (binA launches after -> kernel boundary orders it).

__global__ __launch_bounds__(256) void k_prep(const float* __restrict__ nf, const float* __restrict__ We,
                                              const float* __restrict__ be, _Float16* __restrict__ xh,
                                              int N,
                                              const float* __restrict__ Wl, const float* __restrict__ Wr,
                                              _Float16* __restrict__ WfL, _Float16* __restrict__ WfR,
                                              int* __restrict__ gcnt, int nW) {
    const int bid = blockIdx.x;
    const int tid = threadIdx.x;
    if (bid < EMBB) {
        const int h    = tid & 127;
        const int slot = bid * 2 + (tid >> 7);
        float wr[11];
        #pragma unroll
        for (int k = 0; k < 11; k++) wr[k] = We[h * 11 + k];
        const float bv = be[h];
        for (int n = slot; n < N; n += 2 * EMBB) {
            const float* fr = nf + (size_t)n * 11;
            float acc = bv;
            #pragma unroll
            for (int k = 0; k < 11; k++) acc += fr[k] * wr[k];
            xh[(size_t)n * HID + h] = (_Float16)fmaxf(acc, 0.f);
        }
    } else {
        const int tb = bid - EMBB;              // 0..127
        if (tb == 0) gcnt[tid] = 0;
        const int mat = tb >> 6;                // 64 blocks per matrix
        const float* x = mat ? Wr : Wl;
        _Float16*    o = mat ? WfR : WfL;
        int base = ((tb & 63) * 256 + tid) * 4;
        if (base >= nW) return;
        float4 v = *(const float4*)(x + base);
        f16x4 h = {(_Float16)v.x, (_Float16)v.y, (_Float16)v.z, (_Float16)v.w};
        *(f16x4*)(o + base) = h;
    }
}

// ---------------- CSR phase A: binned counting sort ----------------
// Record = (src<<8)|(dst&255) binned into per-bucket arenas.

__global__ __launch_bounds__(256) void k_binA(const int* __restrict__ src, const int* __restrict__ dst,
                                              int E, int* __restrict__ gcnt, int* __restrict__ arena) {
    __shared__ int lh[256];
    __shared__ int lbase[256];
    __shared__ unsigned short lrank[ACHUNK];
    const int tid = threadIdx.x;
    lh[tid] = 0;
    __syncthreads();
    const int e0 = blockIdx.x * ACHUNK;
    #pragma unroll
    for (int i = 0; i < ACHUNK / 256; i++) {
        int e = e0 + i * 256 + tid;
        if (e < E) {
            int b = dst[e] >> 8;
            lrank[i * 256 + tid] = (unsigned short)atomicAdd(&lh[b], 1);
        }
    }
    __syncthreads();
    if (lh[tid] > 0) lbase[tid] = atomicAdd(&gcnt[tid], lh[tid]);
    __syncthreads();
    #pragma unroll
    for (int i = 0; i < ACHUNK / 256; i++) {
        int e = e0 + i * 256 + tid;
        if (e < E) {
            int d = dst[e];
            int b = d >> 8;
            arena[b * BCAP + lbase[b] + lrank[i * 256 + tid]] = (src[e] << 8) | (d & 255);
        }
    }
}

// ---------------- CSR phase B: per bucket, rowptr + csr_off ----------------
// Direct scattered csr_off writes (dense within the ~16KB bucket segment ->
// L2 merges into lines; grid-limited at 196 blocks so extra LDS pass was
// pure latency).

__global__ __launch_bounds__(256) void k_binB(const int* __restrict__ arena, const int* __restrict__ gcnt,
                                              int N, int E,
                                              int* __restrict__ rowptr, int* __restrict__ csr_off) {
    __shared__ int ncnt[256];
    __shared__ int sbuf[256];
    __shared__ int nstart[256];
    __shared__ int exv[256];
    __shared__ unsigned short rk[BCAP];
    const int b = blockIdx.x, tid = threadIdx.x;

    // bucket-prefix scan (gcnt[tid]=0 for tid>=nbk, zeroed by k_prep)
    int gv = gcnt[tid];
    sbuf[tid] = gv;
    __syncthreads();
    for (int off = 1; off < 256; off <<= 1) {
        int t = (tid >= off) ? sbuf[tid - off] : 0;
        __syncthreads();
        sbuf[tid] += t;
        __syncthreads();
    }
    exv[tid] = sbuf[tid] - gv;    // exclusive prefix
    if (b == 0 && tid == 0) rowptr[N] = E;
    __syncthreads();
    const int seg = exv[b];
    const int cnt = gcnt[b];

    ncnt[tid] = 0;
    __syncthreads();
    for (int k = tid; k < cnt; k += 256) {
        int v = arena[b * BCAP + k];
        rk[k] = (unsigned short)atomicAdd(&ncnt[v & 255], 1);
    }
    __syncthreads();
    int c = ncnt[tid];
    sbuf[tid] = c;
    __syncthreads();
    for (int off = 1; off < 256; off <<= 1) {
        int t = (tid >= off) ? sbuf[tid - off] : 0;
        __syncthreads();
        sbuf[tid] += t;
        __syncthreads();
    }
    int myStart = sbuf[tid] - c;   // exclusive
    nstart[tid] = myStart;
    int n = b * 256 + tid;
    if (n < N) rowptr[n] = seg + myStart;
    __syncthreads();
    for (int k = tid; k < cnt; k += 256) {
        int v = arena[b * BCAP + k];
        int pos = nstart[v & 255] + rk[k];
        csr_off[seg + pos] = v & 0xFFFFFF00;
    }
}

// ---------------- MFMA linear, LDS-resident fp16 W, 2 A-tiles/wave ----------------
// 256 threads / 128 nodes per block (3.1 blocks/CU); epilogue through LDS
// (node stride 136 halves) -> coalesced 16B stores.

__global__ __launch_bounds__(256, 4) void k_linear_mfma(
        const _Float16* __restrict__ xh,
        const _Float16* __restrict__ WfL, const _Float16* __restrict__ WfR,
        const float* __restrict__ bl, const float* __restrict__ br,
        _Float16* __restrict__ xlh, _Float16* __restrict__ xrh, int N) {
    __shared__ _Float16 lds[16384];   // W fp16 swizzled; reused for C transpose
    const int t   = threadIdx.x;
    const int mat = blockIdx.y;
    const _Float16* W = mat ? WfR : WfL;

    for (int g = t; g < 2048; g += 256) {
        int r = g >> 4, cc = g & 15;
        int dsto = r * 128 + ((cc ^ (r & 7)) << 3);      // half units
        *(float4*)&lds[dsto] = *(const float4*)(W + g * 8);
    }
    __syncthreads();

    const int wave = t >> 6;
    const int lane = t & 63;
    const int l16  = lane & 15;
    const int quad = lane >> 4;
    const int n0   = blockIdx.x * 128 + wave * 32;

    int arow0 = n0 + l16;
    int arow1 = n0 + 16 + l16;
    if (arow0 >= N) arow0 = N - 1;     // clamp loads; stores guarded below
    if (arow1 >= N) arow1 = N - 1;

    f32x4 acc[2][8];
    #pragma unroll
    for (int u = 0; u < 2; u++)
        #pragma unroll
        for (int s = 0; s < 8; s++) acc[u][s] = (f32x4){0.f, 0.f, 0.f, 0.f};

    #pragma unroll
    for (int k0 = 0; k0 < HID; k0 += 32) {
        f16x8 a0 = *(const f16x8*)(xh + arow0 * HID + k0 + quad * 8);
        f16x8 a1 = *(const f16x8*)(xh + arow1 * HID + k0 + quad * 8);
        const int cc = (k0 >> 3) + quad;
        #pragma unroll
        for (int s = 0; s < 8; s++) {
            const int row = s * 16 + l16;
            const int off = row * 128 + ((cc ^ (l16 & 7)) << 3);
            f16x8 b = *(const f16x8*)&lds[off];
            acc[0][s] = __builtin_amdgcn_mfma_f32_16x16x32_f16(a0, b, acc[0][s], 0, 0, 0);
            acc[1][s] = __builtin_amdgcn_mfma_f32_16x16x32_f16(a1, b, acc[1][s], 0, 0, 0);
        }
    }

    const float* bias = mat ? br : bl;
    _Float16* dst = mat ? xrh : xlh;
    const int wl = wave & 1;            // wave index within a round

    #pragma unroll
    for (int round = 0; round < 2; round++) {
        __syncthreads();                 // W (or previous round) fully consumed
        if ((wave >> 1) == round) {
            #pragma unroll
            for (int s = 0; s < 8; s++) {
                int col = s * 16 + l16;
                float bv = bias[col];
                #pragma unroll
                for (int u = 0; u < 2; u++) {
                    #pragma unroll
                    for (int r = 0; r < 4; r++) {
                        int nd = wl * 32 + u * 16 + quad * 4 + r;   // 0..63
                        lds[nd * 136 + col] = (_Float16)(acc[u][s][r] + bv);
                    }
                }
            }
        }
        __syncthreads();
        // coalesced dump: 64 nodes x 256B = 1024 x 16B units
        const int base_node = blockIdx.x * 128 + round * 64;
        #pragma unroll
        for (int it = 0; it < 4; it++) {
            int idx = it * 256 + t;
            int node = base_node + (idx >> 4);
            if (node < N)
                *(float4*)(dst + (size_t)node * HID + (idx & 15) * 8) =
                    *(float4*)&lds[(idx >> 4) * 136 + (idx & 15) * 8];
        }
    }
}

// ---------------- Fused attention: wave per node, 4 edge streams ----------------
// 6-pair upfront loads (gather MLP); per-pair exec-guarded compute. Slow path
// (deg>=25, ~2%): depth-2 predicated pipeline.

__global__ __launch_bounds__(256, 8) void k_attn(const _Float16* __restrict__ xlh, const _Float16* __restrict__ xrh,
                                              const int* __restrict__ rowptr, const int* __restrict__ csr_off,
                                              const float* __restrict__ att, const float* __restrict__ bias,
                                              const _Float16* __restrict__ xres, _Float16* __restrict__ outx,
                                              float* __restrict__ out,
                                              int add_res, int want_half, int N) {
    const int wave = threadIdx.x >> 6;
    const int lane = threadIdx.x & 63;
    const int strm = lane >> 4;          // edge stream 0..3
    const int l16  = lane & 15;          // channels [8*l16, 8*l16+8); head = l16>>2
    const int n = blockIdx.x * 4 + wave;
    if (n >= N) return;

    const float4 aA = *(const float4*)(att + 8 * l16);
    const float4 aB = *(const float4*)(att + 8 * l16 + 4);
    const f16x2 a0 = (f16x2){(_Float16)aA.x, (_Float16)aA.y};
    const f16x2 a1 = (f16x2){(_Float16)aA.z, (_Float16)aA.w};
    const f16x2 a2 = (f16x2){(_Float16)aB.x, (_Float16)aB.y};
    const f16x2 a3 = (f16x2){(_Float16)aB.z, (_Float16)aB.w};
    const f16x8 xrv = *(const f16x8*)(xrh + (size_t)n * HID + 8 * l16);
    const f16x2 xr0 = __builtin_shufflevector(xrv, xrv, 0, 1);
    const f16x2 xr1 = __builtin_shufflevector(xrv, xrv, 2, 3);
    const f16x2 xr2 = __builtin_shufflevector(xrv, xrv, 4, 5);
    const f16x2 xr3 = __builtin_shufflevector(xrv, xrv, 6, 7);
    const int s0 = rowptr[n], s1 = rowptr[n + 1];
    const int deg = s1 - s0;

    float den = 0.f;
    f16x2 acc16[4];
    #pragma unroll
    for (int q = 0; q < 4; q++) acc16[q] = (f16x2){(_Float16)0.f, (_Float16)0.f};

    const char* xlb = (const char*)xlh + l16 * 16;  // lane's 16B slice within a row
    const int j = s0 + 2 * strm;                    // stream's first edge

    if (deg > 0 && deg <= 24) {
        // ---- fast path: loads upfront, compute per-pair exec-guarded ----
        const int last = s1 - 1;
        f16x8 r0 = zero8(), r1 = zero8(), r2 = zero8(),
              r3 = zero8(), r4 = zero8(), r5 = zero8();
        if (j < s1) {
            int o0 = csr_off[j];
            int o1 = csr_off[min(j + 1, last)];
            r0 = *(const f16x8*)(xlb + o0);
            r1 = *(const f16x8*)(xlb + o1);
        }
        if (j + 8 < s1) {
            int o2 = csr_off[j + 8];
            int o3 = csr_off[min(j + 9, last)];
            r2 = *(const f16x8*)(xlb + o2);
            r3 = *(const f16x8*)(xlb + o3);
        }
        if (j + 16 < s1) {
            int o4 = csr_off[j + 16];
            int o5 = csr_off[min(j + 17, last)];
            r4 = *(const f16x8*)(xlb + o4);
            r5 = *(const f16x8*)(xlb + o5);
        }

        if (j < s1) {       // pair 0 (execz-skips only for tiny tails)
            float p0 = edge_logit8(r0, xr0, xr1, xr2, xr3, a0, a1, a2, a3);
            float p1 = edge_logit8(r1, xr0, xr1, xr2, xr3, a0, a1, a2, a3);
            p0 = qp_xor_add<0xB1>(p0); p0 = qp_xor_add<0x4E>(p0);
            p1 = qp_xor_add<0xB1>(p1); p1 = qp_xor_add<0x4E>(p1);
            float w0 = __expf(p0);
            float w1 = (j + 1 < s1) ? __expf(p1) : 0.f;
            den += w0 + w1;
            f16x2 wp0 = (f16x2){(_Float16)w0, (_Float16)w0};
            f16x2 wp1 = (f16x2){(_Float16)w1, (_Float16)w1};
            ACC_ROW(wp0, r0)
            ACC_ROW(wp1, r1)
        }
        if (j + 8 < s1) {   // pair 1 (execz-skips whole wave when deg<=8)
            float p2 = edge_logit8(r2, xr0, xr1, xr2, xr3, a0, a1, a2, a3);
            float p3 = edge_logit8(r3, xr0, xr1, xr2, xr3, a0, a1, a2, a3);
            p2 = qp_xor_add<0xB1>(p2); p2 = qp_xor_add<0x4E>(p2);
            p3 = qp_xor_add<0xB1>(p3); p3 = qp_xor_add<0x4E>(p3);
            float w2 = __expf(p2);
            float w3 = (j + 9 < s1) ? __expf(p3) : 0.f;
            den += w2 + w3;
            f16x2 wp2 = (f16x2){(_Float16)w2, (_Float16)w2};
            f16x2 wp3 = (f16x2){(_Float16)w3, (_Float16)w3};
            ACC_ROW(wp2, r2)
            ACC_ROW(wp3, r3)
        }
        if (j + 16 < s1) {  // pair 2 (execz-skips whole wave when deg<=16)
            float p4 = edge_logit8(r4, xr0, xr1, xr2, xr3, a0, a1, a2, a3);
            float p5 = edge_logit8(r5, xr0, xr1, xr2, xr3, a0, a1, a2, a3);
            p4 = qp_xor_add<0xB1>(p4); p4 = qp_xor_add<0x4E>(p4);
            p5 = qp_xor_add<0xB1>(p5); p5 = qp_xor_add<0x4E>(p5);
            float w4 = __expf(p4);
            float w5 = (j + 17 < s1) ? __expf(p5) : 0.f;
            den += w4 + w5;
            f16x2 wp4 = (f16x2){(_Float16)w4, (_Float16)w4};
            f16x2 wp5 = (f16x2){(_Float16)w5, (_Float16)w5};
            ACC_ROW(wp4, r4)
            ACC_ROW(wp5, r5)
        }
    } else if (deg > 24) {
        // ---- slow path: depth-2 pipeline, predicated prefetch ----
        const int last = s1 - 1;
        int jj = j;
        // prologue: all 4 rows valid (deg>=25 => jj+9 <= s0+15 < s1)
        f16x8 pa0 = *(const f16x8*)(xlb + csr_off[jj]);
        f16x8 pb0 = *(const f16x8*)(xlb + csr_off[jj + 1]);
        f16x8 pa1 = *(const f16x8*)(xlb + csr_off[jj + 8]);
        f16x8 pb1 = *(const f16x8*)(xlb + csr_off[jj + 9]);
        int oa = csr_off[min(jj + 16, last)];
        int ob = csr_off[min(jj + 17, last)];
        while (jj < s1) {
            f16x8 ca = pa0, cb = pb0;
            pa0 = pa1; pb0 = pb1;
            if (jj + 16 < s1) {          // predicated prefetch: no dup gathers
                pa1 = *(const f16x8*)(xlb + oa);
                pb1 = *(const f16x8*)(xlb + ob);
                oa = csr_off[min(jj + 24, last)];
                ob = csr_off[min(jj + 25, last)];
            } else { pa1 = zero8(); pb1 = zero8(); }

            float pa = edge_logit8(ca, xr0, xr1, xr2, xr3, a0, a1, a2, a3);
            float pb = edge_logit8(cb, xr0, xr1, xr2, xr3, a0, a1, a2, a3);
            pa = qp_xor_add<0xB1>(pa); pa = qp_xor_add<0x4E>(pa);
            pb = qp_xor_add<0xB1>(pb); pb = qp_xor_add<0x4E>(pb);
            float wa = __expf(pa);
            float wb = (jj + 1 < s1) ? __expf(pb) : 0.f;
            den += wa + wb;
            f16x2 wpa = (f16x2){(_Float16)wa, (_Float16)wa};
            f16x2 wpb = (f16x2){(_Float16)wb, (_Float16)wb};
            ACC_ROW(wpa, ca)
            ACC_ROW(wpb, cb)
            jj += 8;
        }
    }

    // merge the four streams (lane stride 16/32) on packed f16x2
    den += __shfl_xor(den, 16);
    den += __shfl_xor(den, 32);
    #pragma unroll
    for (int q = 0; q < 4; q++) {
        float pk = __builtin_bit_cast(float, acc16[q]);
        acc16[q] += __builtin_bit_cast(f16x2, __shfl_xor(pk, 16));
        pk = __builtin_bit_cast(float, acc16[q]);
        acc16[q] += __builtin_bit_cast(f16x2, __shfl_xor(pk, 32));
    }

    if (strm == 0) {
        float acc[8];
        #pragma unroll
        for (int q = 0; q < 4; q++) {
            acc[2 * q]     = (float)acc16[q][0];
            acc[2 * q + 1] = (float)acc16[q][1];
        }
        float4 bA = *(const float4*)(bias + 8 * l16);
        float4 bB = *(const float4*)(bias + 8 * l16 + 4);
        float b[8] = {bA.x, bA.y, bA.z, bA.w, bB.x, bB.y, bB.z, bB.w};
        float inv = (den > 0.f) ? 1.f / den : 0.f;
        float v[8];
        #pragma unroll
        for (int q = 0; q < 8; q++) v[q] = fmaxf(acc[q] * inv + b[q], 0.f);
        if (add_res) {
            f16x8 r = *(const f16x8*)(xres + (size_t)n * HID + 8 * l16);
            #pragma unroll
            for (int q = 0; q < 8; q++) v[q] += (float)r[q];
        }
        if (want_half) {
            f16x8 h;
            #pragma unroll
            for (int q = 0; q < 8; q++) h[q] = (_Float16)v[q];
            *(f16x8*)(outx + (size_t)n * HID + 8 * l16) = h;
        } else {
            *(float4*)(out + (size_t)n * HID + 8 * l16)     = make_float4(v[0], v[1], v[2], v[3]);
            *(float4*)(out + (size_t)n * HID + 8 * l16 + 4) = make_float4(v[4], v[5], v[6], v[7]);
        }
    }
}

// ---------------- Graph readout: mean + max over nodes ----------------

__global__ __launch_bounds__(256) void k_reduce1(const float* __restrict__ x, int N,
                                                 float* __restrict__ psum, float* __restrict__ pmax) {
    __shared__ float ls[8][HID];
    __shared__ float lm[8][HID];
    const int c4 = (threadIdx.x & 31) << 2;   // channel base
    const int rl = threadIdx.x >> 5;          // row lane 0..7
    const int per = (N + gridDim.x - 1) / gridDim.x;
    const int n0 = blockIdx.x * per, n1 = min(N, n0 + per);
    float4 s = make_float4(0.f, 0.f, 0.f, 0.f);
    float4 m = make_float4(-INFINITY, -INFINITY, -INFINITY, -INFINITY);
    for (int n = n0 + rl; n < n1; n += 8) {
        float4 v = *(const float4*)(x + (size_t)n * HID + c4);
        s.x += v.x; s.y += v.y; s.z += v.z; s.w += v.w;
        m.x = fmaxf(m.x, v.x); m.y = fmaxf(m.y, v.y);
        m.z = fmaxf(m.z, v.z); m.w = fmaxf(m.w, v.w);
    }
    *(float4*)&ls[rl][c4] = s;
    *(float4*)&lm[rl][c4] = m;
    __syncthreads();
    if (rl < 4) {
        float4 a = *(float4*)&ls[rl][c4], bq = *(float4*)&ls[rl + 4][c4];
        a.x += bq.x; a.y += bq.y; a.z += bq.z; a.w += bq.w;
        *(float4*)&ls[rl][c4] = a;
        float4 am = *(float4*)&lm[rl][c4], bm = *(float4*)&lm[rl + 4][c4];
        am.x = fmaxf(am.x, bm.x); am.y = fmaxf(am.y, bm.y);
        am.z = fmaxf(am.z, bm.z); am.w = fmaxf(am.w, bm.w);
        *(float4*)&lm[rl][c4] = am;
    }
    __syncthreads();
    if (rl < 2) {
        float4 a = *(float4*)&ls[rl][c4], bq = *(float4*)&ls[rl + 2][c4];
        a.x += bq.x; a.y += bq.y; a.z += bq.z; a.w += bq.w;
        *(float4*)&ls[rl][c4] = a;
        float4 am = *(float4*)&lm[rl][c4], bm = *(float4*)&lm[rl + 2][c4];
        am.x = fmaxf(am.x, bm.x); am.y = fmaxf(am.y, bm.y);
        am.z = fmaxf(am.z, bm.z); am.w = fmaxf(am.w, bm.w);
        *(float4*)&lm[rl][c4] = am;
    }
    __syncthreads();
    if (rl == 0) {
        float4 a = *(float4*)&ls[0][c4], bq = *(float4*)&ls[1][c4];
        a.x += bq.x; a.y += bq.y; a.z += bq.z; a.w += bq.w;
        *(float4*)(psum + (size_t)blockIdx.x * HID + c4) = a;
        float4 am = *(float4*)&lm[0][c4], bm = *(float4*)&lm[1][c4];
        am.x = fmaxf(am.x, bm.x); am.y = fmaxf(am.y, bm.y);
        am.z = fmaxf(am.z, bm.z); am.w = fmaxf(am.w, bm.w);
        *(float4*)(pmax + (size_t)blockIdx.x * HID + c4) = am;
    }
}

__global__ __launch_bounds__(1024) void k_reduce2(const float* __restrict__ psum, const float* __restrict__ pmax,
                                                  int nb, float* __restrict__ out, float invN) {
    __shared__ float ss[8][HID];
    __shared__ float sm[8][HID];
    int h = threadIdx.x & 127;
    int c = threadIdx.x >> 7;          // chunk 0..7
    int per = nb >> 3;
    float s = 0.f, m = -INFINITY;
    for (int b = c * per; b < (c + 1) * per; b++) {
        s += psum[b * HID + h];
        m = fmaxf(m, pmax[b * HID + h]);
    }
    ss[c][h] = s; sm[c][h] = m;
    __syncthreads();
    if (c < 4) { ss[c][h] += ss[c + 4][h]; sm[c][h] = fmaxf(sm[c][h], sm[c + 4][h]); }
    __syncthreads();
    if (c < 2) { ss[c][h] += ss[c + 2][h]; sm[c][h] = fmaxf(sm[c][h], sm[c + 2][h]); }
    __syncthreads();
    if (c == 0) {
        out[h] = (ss[0][h] + ss[1][h]) * invN;
        out[HID + h] = fmaxf(sm[0][h], sm[1][h]);
    }
}

// ---------------- Launch ----------------

extern "C" void kernel_launch(void* const* d_in, const int* in_sizes, int n_in,
                              void* d_out, int out_size, void* d_ws, size_t ws_size,
                              hipStream_t stream) {
    const float* nf    = (const float*)d_in[0];
    const int*   ei    = (const int*)d_in[1];
    const float* W_emb = (const float*)d_in[3];
    const float* b_emb = (const float*)d_in[4];
    const float* Wl    = (const float*)d_in[5];
    const float* bl    = (const float*)d_in[6];
    const float* Wr    = (const float*)d_in[7];
    const float* br    = (const float*)d_in[8];
    const float* att   = (const float*)d_in[9];
    const float* bias  = (const float*)d_in[10];

    const int N = in_sizes[0] / 11;
    const int E = in_sizes[1] / 2;
    const int* src = ei;
    const int* dst = ei + E;

    float* out  = (float*)d_out;
    float* xout = out + 2 * HID;

    // workspace carve-up
    char* w = (char*)d_ws;
    _Float16* xlh  = (_Float16*)w; w += (size_t)N * HID * 2;
    _Float16* xrh  = (_Float16*)w; w += (size_t)N * HID * 2;
    _Float16* xA   = (_Float16*)w; w += (size_t)N * HID * 2;
    _Float16* xB   = (_Float16*)w; w += (size_t)N * HID * 2;
    _Float16* WfL  = (_Float16*)w; w += (size_t)4 * HID * HID * 2;
    _Float16* WfR  = (_Float16*)w; w += (size_t)4 * HID * HID * 2;
    int*   gcnt    = (int*)w;   w += (size_t)256 * 4;
    int*   rowptr  = (int*)w;   w += (size_t)(N + 1) * 4;
    int*   arena   = (int*)w;   w += (size_t)256 * BCAP * 4;
    int*   csr_off = (int*)w;   w += (size_t)E * 4;
    float* psum    = (float*)w; w += (size_t)R1B * HID * 4;
    float* pmax    = (float*)w; w += (size_t)R1B * HID * 4;

    const int nbk = (N + 255) >> 8;       // 196 buckets
    const int nW = 4 * HID * HID;

    // prep: grid-stride embed + W fp16 conversion + gcnt zeroing
    k_prep<<<EMBB + 128, 256, 0, stream>>>(nf, W_emb, b_emb, xA, N,
                                           Wl, Wr, WfL, WfR, gcnt, nW);

    // CSR build (binned two-phase; binB self-scans bucket prefix)
    k_binA<<<(E + ACHUNK - 1) / ACHUNK, 256, 0, stream>>>(src, dst, E, gcnt, arena);
    k_binB<<<nbk, 256, 0, stream>>>(arena, gcnt, N, E, rowptr, csr_off);

    dim3 lgrid((N + 127) / 128, 2);
    for (int i = 0; i < 4; i++) {
        // ping-pong: even layers read A write B, odd layers read B write A
        const _Float16* xin = (i & 1) ? xB : xA;
        _Float16* xo        = (i & 1) ? xA : xB;
        k_linear_mfma<<<lgrid, 256, 0, stream>>>(xin,
                                                 WfL + (size_t)i * HID * HID, WfR + (size_t)i * HID * HID,
                                                 bl + i * HID, br + i * HID, xlh, xrh, N);
        k_attn<<<(N + 3) / 4, 256, 0, stream>>>(xlh, xrh, rowptr, csr_off,
                                                att + i * HEADS * 32, bias + i * HID,
                                                xin, xo, xout,
                                                i > 0 ? 1 : 0, i < 3 ? 1 : 0, N);
    }

    k_reduce1<<<R1B, 256, 0, stream>>>(xout, N, psum, pmax);
    k_reduce2<<<1, 1024, 0, stream>>>(psum, pmax, R1B, out, 1.0f / N);
}